// Round 1
// baseline (2303.780 us; speedup 1.0000x reference)
//
#include <hip/hip_runtime.h>
#include <cstdint>
#include <cstddef>

#define Nn 50000
#define Ne 800000
#define Ng 1024
#define NFd 32
#define Rr 4
#define Hd 64
#define Od 16
#define MAXD 10
#define NPAD (Nn + 64)

__device__ __forceinline__ float reluf(float v) { return v > 0.f ? v : 0.f; }

// ---- per-edge relation argmax + (tgt,rel) counts + degree counts ----
__global__ void k_rel_cnt(const float4* __restrict__ ea, const int* __restrict__ eidx,
                          int* __restrict__ rel, int* __restrict__ cnt_nr, int* __restrict__ deg) {
    int e = blockIdx.x * 256 + threadIdx.x;
    if (e >= Ne) return;
    float4 a = ea[e];
    int bi = 0; float bv = a.x;
    if (a.y > bv) { bv = a.y; bi = 1; }
    if (a.z > bv) { bv = a.z; bi = 2; }
    if (a.w > bv) { bv = a.w; bi = 3; }
    rel[e] = bi;
    int tgt = eidx[Ne + e];
    atomicAdd(&cnt_nr[tgt * Rr + bi], 1);
    atomicAdd(&deg[tgt], 1);
}

// ---- embedding lookup: wave per node, lanes 0..31 do argmax over x row ----
__global__ void k_embed(const float* __restrict__ x, const float* __restrict__ emb,
                        float* __restrict__ h) {
    int wave = (blockIdx.x * 256 + threadIdx.x) >> 6;
    int lane = threadIdx.x & 63;
    if (wave >= Nn) return;
    float v = (lane < NFd) ? x[(size_t)wave * NFd + lane] : -1e30f;
    int idx = lane;
    #pragma unroll
    for (int off = 16; off >= 1; off >>= 1) {
        float ov = __shfl_down(v, off);
        int oi = __shfl_down(idx, off);
        if (ov > v || (ov == v && oi < idx)) { v = ov; idx = oi; }
    }
    idx = __shfl(idx, 0);
    h[(size_t)wave * Hd + lane] = emb[(size_t)idx * Hd + lane];
}

// ---- degree bucketing (counting sort into 11 buckets, bases padded to x4) ----
__global__ void k_bucket_count(const int* __restrict__ deg, int* __restrict__ bcnt) {
    int n = blockIdx.x * 256 + threadIdx.x;
    if (n >= Nn) return;
    int d = min(deg[n], MAXD);
    atomicAdd(&bcnt[d], 1);
}

__global__ void k_bucket_prefix(const int* __restrict__ bcnt, int* __restrict__ bbase) {
    if (threadIdx.x == 0 && blockIdx.x == 0) {
        int run = 0;
        for (int d = 0; d <= MAXD; d++) { bbase[d] = run; run += (bcnt[d] + 3) & ~3; }
    }
}

__global__ void k_bucket_scatter(const int* __restrict__ deg, const int* __restrict__ bbase,
                                 int* __restrict__ bfill, int* __restrict__ order) {
    int n = blockIdx.x * 256 + threadIdx.x;
    if (n >= Nn) return;
    int d = min(deg[n], MAXD);
    int pos = bbase[d] + atomicAdd(&bfill[d], 1);
    order[pos] = n | (d << 20);
}

// ---- RGCN: sum relu(h[src]) into agg[(tgt,rel)] (mean scaling deferred) ----
__global__ void k_rgcn_agg(const float* __restrict__ hin, const int* __restrict__ eidx,
                           const int* __restrict__ rel, float* __restrict__ agg) {
    int wave = __builtin_amdgcn_readfirstlane((blockIdx.x * 256 + threadIdx.x) >> 6);
    int lane = threadIdx.x & 63;
    int e0 = wave * 4;
    if (e0 >= Ne) return;
    #pragma unroll
    for (int i = 0; i < 4; i++) {
        int e = e0 + i;
        int src = eidx[e];
        int tgt = eidx[Ne + e];
        int r = rel[e];
        float v = reluf(hin[(size_t)src * Hd + lane]);
        if (v != 0.f) unsafeAtomicAdd(&agg[((size_t)tgt * Rr + r) * Hd + lane], v);
    }
}

// ---- RGCN transform: out = sum_r mean_r @ W[r] + relu(h) @ Wroot + b ----
// 4 nodes per wave to amortize weight loads.
__global__ void k_rgcn_xform(const float* __restrict__ hin, const float* __restrict__ agg,
                             const int* __restrict__ cnt_nr, const float* __restrict__ W,
                             const float* __restrict__ Wroot, const float* __restrict__ bias,
                             float* __restrict__ hout) {
    int wave = __builtin_amdgcn_readfirstlane((blockIdx.x * 256 + threadIdx.x) >> 6);
    int lane = threadIdx.x & 63;
    int n0 = wave * 4;
    if (n0 >= Nn) return;
    float bj = bias[lane];
    float acc[4];
    #pragma unroll
    for (int i = 0; i < 4; i++) acc[i] = bj;
    // root term
    for (int k = 0; k < Hd; k++) {
        float w = Wroot[k * Hd + lane];
        #pragma unroll
        for (int i = 0; i < 4; i++) acc[i] += reluf(hin[(size_t)(n0 + i) * Hd + k]) * w;
    }
    // relation terms (mean = sum * inv applied after the k-loop)
    for (int r = 0; r < Rr; r++) {
        const float* Wp = W + (size_t)r * Hd * Hd;
        float tmp[4] = {0.f, 0.f, 0.f, 0.f};
        for (int k = 0; k < Hd; k++) {
            float w = Wp[k * Hd + lane];
            #pragma unroll
            for (int i = 0; i < 4; i++)
                tmp[i] += agg[((size_t)(n0 + i) * Rr + r) * Hd + k] * w;
        }
        #pragma unroll
        for (int i = 0; i < 4; i++) {
            int c = cnt_nr[(n0 + i) * Rr + r];
            float inv = (c > 0) ? 1.f / (float)c : 0.f;
            acc[i] += tmp[i] * inv;
        }
    }
    #pragma unroll
    for (int i = 0; i < 4; i++) hout[(size_t)(n0 + i) * Hd + lane] = acc[i];
}

// ---- MFConv: sum relu(h[src]) into agg2[tgt] ----
__global__ void k_mf_agg(const float* __restrict__ hin, const int* __restrict__ eidx,
                         float* __restrict__ agg2) {
    int wave = __builtin_amdgcn_readfirstlane((blockIdx.x * 256 + threadIdx.x) >> 6);
    int lane = threadIdx.x & 63;
    int e0 = wave * 4;
    if (e0 >= Ne) return;
    #pragma unroll
    for (int i = 0; i < 4; i++) {
        int e = e0 + i;
        int src = eidx[e];
        int tgt = eidx[Ne + e];
        float v = reluf(hin[(size_t)src * Hd + lane]);
        if (v != 0.f) unsafeAtomicAdd(&agg2[(size_t)tgt * Hd + lane], v);
    }
}

// ---- MFConv transform: degree-bucketed so 4 nodes/wave share Wl[d]/Wr[d] ----
__global__ void k_mf_xform(const float* __restrict__ hin, const float* __restrict__ agg2,
                           const int* __restrict__ order, const float* __restrict__ Wl,
                           const float* __restrict__ bl, const float* __restrict__ Wr,
                           float* __restrict__ hout) {
    int wave = __builtin_amdgcn_readfirstlane((blockIdx.x * 256 + threadIdx.x) >> 6);
    int lane = threadIdx.x & 63;
    int g0 = wave * 4;
    if (g0 >= NPAD) return;
    int ent[4];
    #pragma unroll
    for (int i = 0; i < 4; i++) ent[i] = order[g0 + i];
    int d = -1;
    #pragma unroll
    for (int i = 3; i >= 0; i--) if (ent[i] >= 0) d = ent[i] >> 20;
    if (d < 0) return;
    int n[4];
    #pragma unroll
    for (int i = 0; i < 4; i++) n[i] = (ent[i] >= 0) ? (ent[i] & 0xFFFFF) : 0;
    const float* wl = Wl + (size_t)d * Hd * Hd;
    const float* wr = Wr + (size_t)d * Hd * Hd;
    float acc[4] = {0.f, 0.f, 0.f, 0.f};
    for (int k = 0; k < Hd; k++) {
        float a = wl[k * Hd + lane];
        float b = wr[k * Hd + lane];
        #pragma unroll
        for (int i = 0; i < 4; i++)
            acc[i] += agg2[(size_t)n[i] * Hd + k] * a + reluf(hin[(size_t)n[i] * Hd + k]) * b;
    }
    float bb = bl[d * Hd + lane];
    #pragma unroll
    for (int i = 0; i < 4; i++)
        if (ent[i] >= 0) hout[(size_t)n[i] * Hd + lane] = acc[i] + bb;
}

// ---- global add pool (batch_idx is sorted -> mostly single fused atomic) ----
__global__ void k_pool(const float* __restrict__ h, const int* __restrict__ batch,
                       float* __restrict__ g) {
    int wave = __builtin_amdgcn_readfirstlane((blockIdx.x * 256 + threadIdx.x) >> 6);
    int lane = threadIdx.x & 63;
    int n0 = wave * 4;
    if (n0 >= Nn) return;
    int b0 = batch[n0], b1 = batch[n0 + 1], b2 = batch[n0 + 2], b3 = batch[n0 + 3];
    float v0 = h[(size_t)n0 * Hd + lane];
    float v1 = h[(size_t)(n0 + 1) * Hd + lane];
    float v2 = h[(size_t)(n0 + 2) * Hd + lane];
    float v3 = h[(size_t)(n0 + 3) * Hd + lane];
    if (b0 == b1 && b0 == b2 && b0 == b3) {
        unsafeAtomicAdd(&g[(size_t)b0 * Hd + lane], v0 + v1 + v2 + v3);
    } else {
        unsafeAtomicAdd(&g[(size_t)b0 * Hd + lane], v0);
        unsafeAtomicAdd(&g[(size_t)b1 * Hd + lane], v1);
        unsafeAtomicAdd(&g[(size_t)b2 * Hd + lane], v2);
        unsafeAtomicAdd(&g[(size_t)b3 * Hd + lane], v3);
    }
}

// ---- head: relu(g@lin1+b1)@lin2+b2, one wave per graph ----
__global__ void k_head(const float* __restrict__ g, const float* __restrict__ w1,
                       const float* __restrict__ b1, const float* __restrict__ w2,
                       const float* __restrict__ b2, float* __restrict__ out) {
    __shared__ float t[4][Hd];
    int wv = threadIdx.x >> 6;
    int lane = threadIdx.x & 63;
    int gi = blockIdx.x * 4 + wv;
    float acc = b1[lane];
    for (int k = 0; k < Hd; k++) acc += g[(size_t)gi * Hd + k] * w1[k * Hd + lane];
    t[wv][lane] = reluf(acc);
    __syncthreads();
    if (lane < Od) {
        float o = b2[lane];
        for (int k = 0; k < Hd; k++) o += t[wv][k] * w2[k * Od + lane];
        out[(size_t)gi * Od + lane] = o;
    }
}

extern "C" void kernel_launch(void* const* d_in, const int* in_sizes, int n_in,
                              void* d_out, int out_size, void* d_ws, size_t ws_size,
                              hipStream_t stream) {
    const float* x      = (const float*)d_in[0];
    const float* ea     = (const float*)d_in[1];
    const int*   eidx   = (const int*)d_in[2];
    const int*   batch  = (const int*)d_in[3];
    const float* emb    = (const float*)d_in[4];
    const float* lin1_w = (const float*)d_in[5];
    const float* lin1_b = (const float*)d_in[6];
    const float* lin2_w = (const float*)d_in[7];
    const float* lin2_b = (const float*)d_in[8];
    const float* rgcn_w[2]    = {(const float*)d_in[9],  (const float*)d_in[15]};
    const float* rgcn_root[2] = {(const float*)d_in[10], (const float*)d_in[16]};
    const float* rgcn_b[2]    = {(const float*)d_in[11], (const float*)d_in[17]};
    const float* mf_wl[2]     = {(const float*)d_in[12], (const float*)d_in[18]};
    const float* mf_bl[2]     = {(const float*)d_in[13], (const float*)d_in[19]};
    const float* mf_wr[2]     = {(const float*)d_in[14], (const float*)d_in[20]};

    char* p = (char*)d_ws;
    float* h0   = (float*)p; p += sizeof(float) * (size_t)Nn * Hd;
    float* h1   = (float*)p; p += sizeof(float) * (size_t)Nn * Hd;
    float* agg  = (float*)p; p += sizeof(float) * (size_t)Nn * Rr * Hd;
    float* gbuf = (float*)p; p += sizeof(float) * (size_t)Ng * Hd;
    int* rel    = (int*)p;   p += sizeof(int) * (size_t)Ne;
    int* cnt_nr = (int*)p;   p += sizeof(int) * (size_t)Nn * Rr;
    int* deg    = (int*)p;   p += sizeof(int) * (size_t)Nn;
    int* bcnt   = (int*)p;   p += sizeof(int) * 16;
    int* bfill  = (int*)p;   p += sizeof(int) * 16;
    int* bbase  = (int*)p;   p += sizeof(int) * 16;
    int* order  = (int*)p;   p += sizeof(int) * (size_t)NPAD;

    // zero counters: cnt_nr, deg, bcnt, bfill, bbase are contiguous
    hipMemsetAsync(cnt_nr, 0, sizeof(int) * ((size_t)Nn * Rr + Nn + 48), stream);
    hipMemsetAsync(order, 0xFF, sizeof(int) * (size_t)NPAD, stream);
    hipMemsetAsync(gbuf, 0, sizeof(float) * (size_t)Ng * Hd, stream);

    k_rel_cnt<<<Ne / 256, 256, 0, stream>>>((const float4*)ea, eidx, rel, cnt_nr, deg);
    k_embed<<<Nn / 4, 256, 0, stream>>>(x, emb, h0);
    k_bucket_count<<<(Nn + 255) / 256, 256, 0, stream>>>(deg, bcnt);
    k_bucket_prefix<<<1, 64, 0, stream>>>(bcnt, bbase);
    k_bucket_scatter<<<(Nn + 255) / 256, 256, 0, stream>>>(deg, bbase, bfill, order);

    float* hin = h0;
    float* hout = h1;
    for (int b = 0; b < 2; b++) {
        hipMemsetAsync(agg, 0, sizeof(float) * (size_t)Nn * Rr * Hd, stream);
        k_rgcn_agg<<<Ne / 16, 256, 0, stream>>>(hin, eidx, rel, agg);
        k_rgcn_xform<<<Nn / 16, 256, 0, stream>>>(hin, agg, cnt_nr, rgcn_w[b], rgcn_root[b],
                                                  rgcn_b[b], hout);
        hipMemsetAsync(agg, 0, sizeof(float) * (size_t)Nn * Hd, stream);
        k_mf_agg<<<Ne / 16, 256, 0, stream>>>(hout, eidx, agg);
        k_mf_xform<<<(NPAD / 4 + 3) / 4, 256, 0, stream>>>(hout, agg, order, mf_wl[b], mf_bl[b],
                                                           mf_wr[b], hin);
        // block output is back in hin for the next block
    }
    k_pool<<<Nn / 16, 256, 0, stream>>>(hin, batch, gbuf);
    k_head<<<Ng / 4, 256, 0, stream>>>(gbuf, lin1_w, lin1_b, lin2_w, lin2_b, (float*)d_out);
}

// Round 2
// 1143.963 us; speedup vs baseline: 2.0139x; 2.0139x over previous
//
#include <hip/hip_runtime.h>
#include <cstdint>
#include <cstddef>

#define Nn 50000
#define Ne 800000
#define Ng 1024
#define NFd 32
#define Rr 4
#define Hd 64
#define Od 16
#define MAXD 10
#define NPAD (Nn + 64)

__device__ __forceinline__ float reluf(float v) { return v > 0.f ? v : 0.f; }

// ---- per-edge relation argmax + (tgt,rel) counts ----
__global__ void k_rel_cnt(const float4* __restrict__ ea, const int* __restrict__ eidx,
                          int* __restrict__ rel, int* __restrict__ cnt_nr) {
    int e = blockIdx.x * 256 + threadIdx.x;
    if (e >= Ne) return;
    float4 a = ea[e];
    int bi = 0; float bv = a.x;
    if (a.y > bv) { bv = a.y; bi = 1; }
    if (a.z > bv) { bv = a.z; bi = 2; }
    if (a.w > bv) { bv = a.w; bi = 3; }
    rel[e] = bi;
    int tgt = eidx[Ne + e];
    atomicAdd(&cnt_nr[tgt * Rr + bi], 1);
}

// ---- embedding lookup: wave per node, lanes 0..31 do argmax over x row ----
__global__ void k_embed(const float* __restrict__ x, const float* __restrict__ emb,
                        float* __restrict__ h) {
    int wave = (blockIdx.x * 256 + threadIdx.x) >> 6;
    int lane = threadIdx.x & 63;
    if (wave >= Nn) return;
    float v = (lane < NFd) ? x[(size_t)wave * NFd + lane] : -1e30f;
    int idx = lane;
    #pragma unroll
    for (int off = 16; off >= 1; off >>= 1) {
        float ov = __shfl_down(v, off);
        int oi = __shfl_down(idx, off);
        if (ov > v || (ov == v && oi < idx)) { v = ov; idx = oi; }
    }
    idx = __shfl(idx, 0);
    h[(size_t)wave * Hd + lane] = emb[(size_t)idx * Hd + lane];
}

// ---- degree bucketing: hierarchical histogram (LDS per block, 11 global atomics/block) ----
__global__ void k_bucket_count(const int4* __restrict__ cnt_nr4, int* __restrict__ bcnt) {
    __shared__ int hist[16];
    if (threadIdx.x < 16) hist[threadIdx.x] = 0;
    __syncthreads();
    int n = blockIdx.x * 256 + threadIdx.x;
    if (n < Nn) {
        int4 c = cnt_nr4[n];
        int d = min(c.x + c.y + c.z + c.w, MAXD);
        atomicAdd(&hist[d], 1);
    }
    __syncthreads();
    if (threadIdx.x < 16) {
        int h = hist[threadIdx.x];
        if (h > 0) atomicAdd(&bcnt[threadIdx.x], h);
    }
}

__global__ void k_bucket_prefix(const int* __restrict__ bcnt, int* __restrict__ bbase) {
    if (threadIdx.x == 0 && blockIdx.x == 0) {
        int run = 0;
        for (int d = 0; d <= MAXD; d++) { bbase[d] = run; run += (bcnt[d] + 3) & ~3; }
    }
}

__global__ void k_bucket_scatter(const int4* __restrict__ cnt_nr4, const int* __restrict__ bbase,
                                 int* __restrict__ bfill, int* __restrict__ order) {
    __shared__ int hist[16];
    __shared__ int base[16];
    if (threadIdx.x < 16) hist[threadIdx.x] = 0;
    __syncthreads();
    int n = blockIdx.x * 256 + threadIdx.x;
    int d = 0, rank = 0;
    bool valid = (n < Nn);
    if (valid) {
        int4 c = cnt_nr4[n];
        d = min(c.x + c.y + c.z + c.w, MAXD);
        rank = atomicAdd(&hist[d], 1);
    }
    __syncthreads();
    if (threadIdx.x < 16) {
        int h = hist[threadIdx.x];
        base[threadIdx.x] = (h > 0) ? atomicAdd(&bfill[threadIdx.x], h) : 0;
    }
    __syncthreads();
    if (valid) order[bbase[d] + base[d] + rank] = n | (d << 20);
}

// ---- RGCN: sum relu(h[src]) into agg[(tgt,rel)] (mean scaling deferred) ----
__global__ void k_rgcn_agg(const float* __restrict__ hin, const int* __restrict__ eidx,
                           const int* __restrict__ rel, float* __restrict__ agg) {
    int wave = __builtin_amdgcn_readfirstlane((blockIdx.x * 256 + threadIdx.x) >> 6);
    int lane = threadIdx.x & 63;
    int e0 = wave * 4;
    if (e0 >= Ne) return;
    #pragma unroll
    for (int i = 0; i < 4; i++) {
        int e = e0 + i;
        int src = eidx[e];
        int tgt = eidx[Ne + e];
        int r = rel[e];
        float v = reluf(hin[(size_t)src * Hd + lane]);
        if (v != 0.f) unsafeAtomicAdd(&agg[((size_t)tgt * Rr + r) * Hd + lane], v);
    }
}

// ---- RGCN transform: out = sum_r mean_r @ W[r] + relu(h) @ Wroot + b ----
__global__ void k_rgcn_xform(const float* __restrict__ hin, const float* __restrict__ agg,
                             const int* __restrict__ cnt_nr, const float* __restrict__ W,
                             const float* __restrict__ Wroot, const float* __restrict__ bias,
                             float* __restrict__ hout) {
    int wave = __builtin_amdgcn_readfirstlane((blockIdx.x * 256 + threadIdx.x) >> 6);
    int lane = threadIdx.x & 63;
    int n0 = wave * 4;
    if (n0 >= Nn) return;
    float bj = bias[lane];
    float acc[4];
    #pragma unroll
    for (int i = 0; i < 4; i++) acc[i] = bj;
    // root term
    for (int k = 0; k < Hd; k++) {
        float w = Wroot[k * Hd + lane];
        #pragma unroll
        for (int i = 0; i < 4; i++) acc[i] += reluf(hin[(size_t)(n0 + i) * Hd + k]) * w;
    }
    // relation terms (mean = sum * inv applied after the k-loop)
    for (int r = 0; r < Rr; r++) {
        const float* Wp = W + (size_t)r * Hd * Hd;
        float tmp[4] = {0.f, 0.f, 0.f, 0.f};
        for (int k = 0; k < Hd; k++) {
            float w = Wp[k * Hd + lane];
            #pragma unroll
            for (int i = 0; i < 4; i++)
                tmp[i] += agg[((size_t)(n0 + i) * Rr + r) * Hd + k] * w;
        }
        #pragma unroll
        for (int i = 0; i < 4; i++) {
            int c = cnt_nr[(n0 + i) * Rr + r];
            float inv = (c > 0) ? 1.f / (float)c : 0.f;
            acc[i] += tmp[i] * inv;
        }
    }
    #pragma unroll
    for (int i = 0; i < 4; i++) hout[(size_t)(n0 + i) * Hd + lane] = acc[i];
}

// ---- MFConv: sum relu(h[src]) into agg2[tgt] ----
__global__ void k_mf_agg(const float* __restrict__ hin, const int* __restrict__ eidx,
                         float* __restrict__ agg2) {
    int wave = __builtin_amdgcn_readfirstlane((blockIdx.x * 256 + threadIdx.x) >> 6);
    int lane = threadIdx.x & 63;
    int e0 = wave * 4;
    if (e0 >= Ne) return;
    #pragma unroll
    for (int i = 0; i < 4; i++) {
        int e = e0 + i;
        int src = eidx[e];
        int tgt = eidx[Ne + e];
        float v = reluf(hin[(size_t)src * Hd + lane]);
        if (v != 0.f) unsafeAtomicAdd(&agg2[(size_t)tgt * Hd + lane], v);
    }
}

// ---- MFConv transform: degree-bucketed so 4 nodes/wave share Wl[d]/Wr[d] ----
__global__ void k_mf_xform(const float* __restrict__ hin, const float* __restrict__ agg2,
                           const int* __restrict__ order, const float* __restrict__ Wl,
                           const float* __restrict__ bl, const float* __restrict__ Wr,
                           float* __restrict__ hout) {
    int wave = __builtin_amdgcn_readfirstlane((blockIdx.x * 256 + threadIdx.x) >> 6);
    int lane = threadIdx.x & 63;
    int g0 = wave * 4;
    if (g0 >= NPAD) return;
    int ent[4];
    #pragma unroll
    for (int i = 0; i < 4; i++) ent[i] = order[g0 + i];
    int d = -1;
    #pragma unroll
    for (int i = 3; i >= 0; i--) if (ent[i] >= 0) d = ent[i] >> 20;
    if (d < 0) return;
    int n[4];
    #pragma unroll
    for (int i = 0; i < 4; i++) n[i] = (ent[i] >= 0) ? (ent[i] & 0xFFFFF) : 0;
    const float* wl = Wl + (size_t)d * Hd * Hd;
    const float* wr = Wr + (size_t)d * Hd * Hd;
    float acc[4] = {0.f, 0.f, 0.f, 0.f};
    for (int k = 0; k < Hd; k++) {
        float a = wl[k * Hd + lane];
        float b = wr[k * Hd + lane];
        #pragma unroll
        for (int i = 0; i < 4; i++)
            acc[i] += agg2[(size_t)n[i] * Hd + k] * a + reluf(hin[(size_t)n[i] * Hd + k]) * b;
    }
    float bb = bl[d * Hd + lane];
    #pragma unroll
    for (int i = 0; i < 4; i++)
        if (ent[i] >= 0) hout[(size_t)n[i] * Hd + lane] = acc[i] + bb;
}

// ---- global add pool (batch_idx is sorted -> mostly single fused atomic) ----
__global__ void k_pool(const float* __restrict__ h, const int* __restrict__ batch,
                       float* __restrict__ g) {
    int wave = __builtin_amdgcn_readfirstlane((blockIdx.x * 256 + threadIdx.x) >> 6);
    int lane = threadIdx.x & 63;
    int n0 = wave * 4;
    if (n0 >= Nn) return;
    int b0 = batch[n0], b1 = batch[n0 + 1], b2 = batch[n0 + 2], b3 = batch[n0 + 3];
    float v0 = h[(size_t)n0 * Hd + lane];
    float v1 = h[(size_t)(n0 + 1) * Hd + lane];
    float v2 = h[(size_t)(n0 + 2) * Hd + lane];
    float v3 = h[(size_t)(n0 + 3) * Hd + lane];
    if (b0 == b1 && b0 == b2 && b0 == b3) {
        unsafeAtomicAdd(&g[(size_t)b0 * Hd + lane], v0 + v1 + v2 + v3);
    } else {
        unsafeAtomicAdd(&g[(size_t)b0 * Hd + lane], v0);
        unsafeAtomicAdd(&g[(size_t)b1 * Hd + lane], v1);
        unsafeAtomicAdd(&g[(size_t)b2 * Hd + lane], v2);
        unsafeAtomicAdd(&g[(size_t)b3 * Hd + lane], v3);
    }
}

// ---- head: relu(g@lin1+b1)@lin2+b2, one wave per graph ----
__global__ void k_head(const float* __restrict__ g, const float* __restrict__ w1,
                       const float* __restrict__ b1, const float* __restrict__ w2,
                       const float* __restrict__ b2, float* __restrict__ out) {
    __shared__ float t[4][Hd];
    int wv = threadIdx.x >> 6;
    int lane = threadIdx.x & 63;
    int gi = blockIdx.x * 4 + wv;
    float acc = b1[lane];
    for (int k = 0; k < Hd; k++) acc += g[(size_t)gi * Hd + k] * w1[k * Hd + lane];
    t[wv][lane] = reluf(acc);
    __syncthreads();
    if (lane < Od) {
        float o = b2[lane];
        for (int k = 0; k < Hd; k++) o += t[wv][k] * w2[k * Od + lane];
        out[(size_t)gi * Od + lane] = o;
    }
}

extern "C" void kernel_launch(void* const* d_in, const int* in_sizes, int n_in,
                              void* d_out, int out_size, void* d_ws, size_t ws_size,
                              hipStream_t stream) {
    const float* x      = (const float*)d_in[0];
    const float* ea     = (const float*)d_in[1];
    const int*   eidx   = (const int*)d_in[2];
    const int*   batch  = (const int*)d_in[3];
    const float* emb    = (const float*)d_in[4];
    const float* lin1_w = (const float*)d_in[5];
    const float* lin1_b = (const float*)d_in[6];
    const float* lin2_w = (const float*)d_in[7];
    const float* lin2_b = (const float*)d_in[8];
    const float* rgcn_w[2]    = {(const float*)d_in[9],  (const float*)d_in[15]};
    const float* rgcn_root[2] = {(const float*)d_in[10], (const float*)d_in[16]};
    const float* rgcn_b[2]    = {(const float*)d_in[11], (const float*)d_in[17]};
    const float* mf_wl[2]     = {(const float*)d_in[12], (const float*)d_in[18]};
    const float* mf_bl[2]     = {(const float*)d_in[13], (const float*)d_in[19]};
    const float* mf_wr[2]     = {(const float*)d_in[14], (const float*)d_in[20]};

    char* p = (char*)d_ws;
    float* h0   = (float*)p; p += sizeof(float) * (size_t)Nn * Hd;
    float* h1   = (float*)p; p += sizeof(float) * (size_t)Nn * Hd;
    float* agg  = (float*)p; p += sizeof(float) * (size_t)Nn * Rr * Hd;
    float* gbuf = (float*)p; p += sizeof(float) * (size_t)Ng * Hd;
    int* rel    = (int*)p;   p += sizeof(int) * (size_t)Ne;
    int* cnt_nr = (int*)p;   p += sizeof(int) * (size_t)Nn * Rr;
    int* bcnt   = (int*)p;   p += sizeof(int) * 16;
    int* bfill  = (int*)p;   p += sizeof(int) * 16;
    int* bbase  = (int*)p;   p += sizeof(int) * 16;
    int* order  = (int*)p;   p += sizeof(int) * (size_t)NPAD;

    // zero counters: cnt_nr, bcnt, bfill, bbase are contiguous
    hipMemsetAsync(cnt_nr, 0, sizeof(int) * ((size_t)Nn * Rr + 48), stream);
    hipMemsetAsync(order, 0xFF, sizeof(int) * (size_t)NPAD, stream);
    hipMemsetAsync(gbuf, 0, sizeof(float) * (size_t)Ng * Hd, stream);

    k_rel_cnt<<<Ne / 256, 256, 0, stream>>>((const float4*)ea, eidx, rel, cnt_nr);
    k_embed<<<Nn / 4, 256, 0, stream>>>(x, emb, h0);
    k_bucket_count<<<(Nn + 255) / 256, 256, 0, stream>>>((const int4*)cnt_nr, bcnt);
    k_bucket_prefix<<<1, 64, 0, stream>>>(bcnt, bbase);
    k_bucket_scatter<<<(Nn + 255) / 256, 256, 0, stream>>>((const int4*)cnt_nr, bbase, bfill, order);

    float* hin = h0;
    float* hout = h1;
    for (int b = 0; b < 2; b++) {
        hipMemsetAsync(agg, 0, sizeof(float) * (size_t)Nn * Rr * Hd, stream);
        k_rgcn_agg<<<Ne / 16, 256, 0, stream>>>(hin, eidx, rel, agg);
        k_rgcn_xform<<<Nn / 16, 256, 0, stream>>>(hin, agg, cnt_nr, rgcn_w[b], rgcn_root[b],
                                                  rgcn_b[b], hout);
        hipMemsetAsync(agg, 0, sizeof(float) * (size_t)Nn * Hd, stream);
        k_mf_agg<<<Ne / 16, 256, 0, stream>>>(hout, eidx, agg);
        k_mf_xform<<<(NPAD / 4 + 3) / 4, 256, 0, stream>>>(hout, agg, order, mf_wl[b], mf_bl[b],
                                                           mf_wr[b], hin);
        // block output is back in hin for the next block
    }
    k_pool<<<Nn / 16, 256, 0, stream>>>(hin, batch, gbuf);
    k_head<<<Ng / 4, 256, 0, stream>>>(gbuf, lin1_w, lin1_b, lin2_w, lin2_b, (float*)d_out);
}

// Round 3
// 726.511 us; speedup vs baseline: 3.1710x; 1.5746x over previous
//
#include <hip/hip_runtime.h>
#include <cstdint>
#include <cstddef>

#define Nn 50000
#define Ne 800000
#define Ng 1024
#define NFd 32
#define Rr 4
#define Hd 64
#define Od 16
#define MAXD 10
#define NPAD (Nn + 64)
#define NSEG (Nn * Rr)
#define SCAN_BLK ((NSEG + 255) / 256)

__device__ __forceinline__ float reluf(float v) { return v > 0.f ? v : 0.f; }

// ---- per-edge relation argmax -> segment id (tgt*R+rel) + segment histogram ----
__global__ void k_rel_seg(const float4* __restrict__ ea, const int* __restrict__ eidx,
                          int* __restrict__ seg, int* __restrict__ cnt) {
    int e = blockIdx.x * 256 + threadIdx.x;
    if (e >= Ne) return;
    float4 a = ea[e];
    int bi = 0; float bv = a.x;
    if (a.y > bv) { bv = a.y; bi = 1; }
    if (a.z > bv) { bv = a.z; bi = 2; }
    if (a.w > bv) { bv = a.w; bi = 3; }
    int s = eidx[Ne + e] * Rr + bi;
    seg[e] = s;
    atomicAdd(&cnt[s], 1);
}

// ---- 3-kernel exclusive scan over cnt[NSEG] -> off[NSEG+1] ----
__global__ void k_scan1(const int* __restrict__ cnt, int* __restrict__ off,
                        int* __restrict__ bsum) {
    __shared__ int s[256];
    int t = threadIdx.x;
    int idx = blockIdx.x * 256 + t;
    int v = (idx < NSEG) ? cnt[idx] : 0;
    s[t] = v;
    __syncthreads();
    #pragma unroll
    for (int o = 1; o < 256; o <<= 1) {
        int x = (t >= o) ? s[t - o] : 0;
        __syncthreads();
        s[t] += x;
        __syncthreads();
    }
    if (idx < NSEG) off[idx] = s[t] - v;            // exclusive
    if (t == 255) bsum[blockIdx.x] = s[255];
}

__global__ void k_scan2(int* __restrict__ bsum) {
    __shared__ int s[1024];
    int t = threadIdx.x;
    int v = (t < SCAN_BLK) ? bsum[t] : 0;
    s[t] = v;
    __syncthreads();
    #pragma unroll
    for (int o = 1; o < 1024; o <<= 1) {
        int x = (t >= o) ? s[t - o] : 0;
        __syncthreads();
        s[t] += x;
        __syncthreads();
    }
    if (t < SCAN_BLK) bsum[t] = s[t] - v;           // exclusive block bases
}

__global__ void k_scan3(int* __restrict__ off, const int* __restrict__ bsum,
                        int* __restrict__ fill) {
    int idx = blockIdx.x * 256 + threadIdx.x;
    if (idx == 0) off[NSEG] = Ne;
    if (idx >= NSEG) return;
    int v = off[idx] + bsum[blockIdx.x];
    off[idx] = v;
    fill[idx] = v;
}

// ---- scatter edges into segment-sorted order (store src only) ----
__global__ void k_scatter(const int* __restrict__ eidx, const int* __restrict__ seg,
                          int* __restrict__ fill, int* __restrict__ sorted_src) {
    int e = blockIdx.x * 256 + threadIdx.x;
    if (e >= Ne) return;
    int pos = atomicAdd(&fill[seg[e]], 1);
    sorted_src[pos] = eidx[e];
}

// ---- embedding lookup: wave per node, lanes 0..31 do argmax over x row ----
__global__ void k_embed(const float* __restrict__ x, const float* __restrict__ emb,
                        float* __restrict__ h) {
    int wave = (blockIdx.x * 256 + threadIdx.x) >> 6;
    int lane = threadIdx.x & 63;
    if (wave >= Nn) return;
    float v = (lane < NFd) ? x[(size_t)wave * NFd + lane] : -1e30f;
    int idx = lane;
    #pragma unroll
    for (int off = 16; off >= 1; off >>= 1) {
        float ov = __shfl_down(v, off);
        int oi = __shfl_down(idx, off);
        if (ov > v || (ov == v && oi < idx)) { v = ov; idx = oi; }
    }
    idx = __shfl(idx, 0);
    h[(size_t)wave * Hd + lane] = emb[(size_t)idx * Hd + lane];
}

// ---- degree bucketing from CSR offsets (LDS hist, 11 global atomics/block) ----
__global__ void k_bucket_count(const int* __restrict__ off, int* __restrict__ bcnt) {
    __shared__ int hist[16];
    if (threadIdx.x < 16) hist[threadIdx.x] = 0;
    __syncthreads();
    int n = blockIdx.x * 256 + threadIdx.x;
    if (n < Nn) {
        int d = min(off[n * Rr + Rr] - off[n * Rr], MAXD);
        atomicAdd(&hist[d], 1);
    }
    __syncthreads();
    if (threadIdx.x < 16) {
        int h = hist[threadIdx.x];
        if (h > 0) atomicAdd(&bcnt[threadIdx.x], h);
    }
}

__global__ void k_bucket_prefix(const int* __restrict__ bcnt, int* __restrict__ bbase) {
    if (threadIdx.x == 0 && blockIdx.x == 0) {
        int run = 0;
        for (int d = 0; d <= MAXD; d++) { bbase[d] = run; run += (bcnt[d] + 3) & ~3; }
    }
}

__global__ void k_bucket_scatter(const int* __restrict__ off, const int* __restrict__ bbase,
                                 int* __restrict__ bfill, int* __restrict__ order) {
    __shared__ int hist[16];
    __shared__ int base[16];
    if (threadIdx.x < 16) hist[threadIdx.x] = 0;
    __syncthreads();
    int n = blockIdx.x * 256 + threadIdx.x;
    int d = 0, rank = 0;
    bool valid = (n < Nn);
    if (valid) {
        d = min(off[n * Rr + Rr] - off[n * Rr], MAXD);
        rank = atomicAdd(&hist[d], 1);
    }
    __syncthreads();
    if (threadIdx.x < 16) {
        int h = hist[threadIdx.x];
        base[threadIdx.x] = (h > 0) ? atomicAdd(&bfill[threadIdx.x], h) : 0;
    }
    __syncthreads();
    if (valid) order[bbase[d] + base[d] + rank] = n | (d << 20);
}

// ---- RGCN: segmented MEAN of relu(h[src]) per (tgt,rel); wave per segment ----
__global__ void k_rgcn_agg(const float* __restrict__ hin, const int* __restrict__ off,
                           const int* __restrict__ sorted_src, float* __restrict__ agg) {
    int s = __builtin_amdgcn_readfirstlane((blockIdx.x * 256 + threadIdx.x) >> 6);
    int lane = threadIdx.x & 63;
    if (s >= NSEG) return;
    int s0 = __builtin_amdgcn_readfirstlane(off[s]);
    int s1 = __builtin_amdgcn_readfirstlane(off[s + 1]);
    float sum = 0.f;
    for (int e = s0; e < s1; e++) {
        int src = __builtin_amdgcn_readfirstlane(sorted_src[e]);
        sum += reluf(hin[(size_t)src * Hd + lane]);
    }
    float inv = (s1 > s0) ? 1.f / (float)(s1 - s0) : 0.f;
    agg[(size_t)s * Hd + lane] = sum * inv;
}

// ---- RGCN transform: out = relu(sum_r mean_r @ W[r] + relu(h) @ Wroot + b) ----
// (downstream only consumes relu(out), so fuse the relu into the store)
__global__ void k_rgcn_xform(const float* __restrict__ hin, const float* __restrict__ agg,
                             const float* __restrict__ W, const float* __restrict__ Wroot,
                             const float* __restrict__ bias, float* __restrict__ hout) {
    int wave = __builtin_amdgcn_readfirstlane((blockIdx.x * 256 + threadIdx.x) >> 6);
    int lane = threadIdx.x & 63;
    int n0 = wave * 4;
    if (n0 >= Nn) return;
    float bj = bias[lane];
    float acc[4];
    #pragma unroll
    for (int i = 0; i < 4; i++) acc[i] = bj;
    // root term
    for (int k = 0; k < Hd; k++) {
        float w = Wroot[k * Hd + lane];
        #pragma unroll
        for (int i = 0; i < 4; i++) acc[i] += reluf(hin[(size_t)(n0 + i) * Hd + k]) * w;
    }
    // relation terms (agg already holds the mean)
    for (int r = 0; r < Rr; r++) {
        const float* Wp = W + (size_t)r * Hd * Hd;
        for (int k = 0; k < Hd; k++) {
            float w = Wp[k * Hd + lane];
            #pragma unroll
            for (int i = 0; i < 4; i++)
                acc[i] += agg[((size_t)(n0 + i) * Rr + r) * Hd + k] * w;
        }
    }
    #pragma unroll
    for (int i = 0; i < 4; i++) hout[(size_t)(n0 + i) * Hd + lane] = reluf(acc[i]);
}

// ---- MFConv: segmented SUM of h[src] per tgt (h already relu'd); wave per node ----
__global__ void k_mf_agg(const float* __restrict__ hin, const int* __restrict__ off,
                         const int* __restrict__ sorted_src, float* __restrict__ agg2) {
    int n = __builtin_amdgcn_readfirstlane((blockIdx.x * 256 + threadIdx.x) >> 6);
    int lane = threadIdx.x & 63;
    if (n >= Nn) return;
    int s0 = __builtin_amdgcn_readfirstlane(off[n * Rr]);
    int s1 = __builtin_amdgcn_readfirstlane(off[n * Rr + Rr]);
    float sum = 0.f;
    for (int e = s0; e < s1; e++) {
        int src = __builtin_amdgcn_readfirstlane(sorted_src[e]);
        sum += hin[(size_t)src * Hd + lane];
    }
    agg2[(size_t)n * Hd + lane] = sum;
}

// ---- MFConv transform: degree-bucketed so 4 nodes/wave share Wl[d]/Wr[d] ----
__global__ void k_mf_xform(const float* __restrict__ hin, const float* __restrict__ agg2,
                           const int* __restrict__ order, const float* __restrict__ Wl,
                           const float* __restrict__ bl, const float* __restrict__ Wr,
                           float* __restrict__ hout) {
    int wave = __builtin_amdgcn_readfirstlane((blockIdx.x * 256 + threadIdx.x) >> 6);
    int lane = threadIdx.x & 63;
    int g0 = wave * 4;
    if (g0 >= NPAD) return;
    int ent[4];
    #pragma unroll
    for (int i = 0; i < 4; i++) ent[i] = order[g0 + i];
    int d = -1;
    #pragma unroll
    for (int i = 3; i >= 0; i--) if (ent[i] >= 0) d = ent[i] >> 20;
    if (d < 0) return;
    int n[4];
    #pragma unroll
    for (int i = 0; i < 4; i++) n[i] = (ent[i] >= 0) ? (ent[i] & 0xFFFFF) : 0;
    const float* wl = Wl + (size_t)d * Hd * Hd;
    const float* wr = Wr + (size_t)d * Hd * Hd;
    float acc[4] = {0.f, 0.f, 0.f, 0.f};
    for (int k = 0; k < Hd; k++) {
        float a = wl[k * Hd + lane];
        float b = wr[k * Hd + lane];
        #pragma unroll
        for (int i = 0; i < 4; i++)
            acc[i] += agg2[(size_t)n[i] * Hd + k] * a + hin[(size_t)n[i] * Hd + k] * b;
    }
    float bb = bl[d * Hd + lane];
    #pragma unroll
    for (int i = 0; i < 4; i++)
        if (ent[i] >= 0) hout[(size_t)n[i] * Hd + lane] = acc[i] + bb;
}

// ---- global add pool (batch_idx is sorted -> mostly single fused atomic) ----
__global__ void k_pool(const float* __restrict__ h, const int* __restrict__ batch,
                       float* __restrict__ g) {
    int wave = __builtin_amdgcn_readfirstlane((blockIdx.x * 256 + threadIdx.x) >> 6);
    int lane = threadIdx.x & 63;
    int n0 = wave * 4;
    if (n0 >= Nn) return;
    int b0 = batch[n0], b1 = batch[n0 + 1], b2 = batch[n0 + 2], b3 = batch[n0 + 3];
    float v0 = h[(size_t)n0 * Hd + lane];
    float v1 = h[(size_t)(n0 + 1) * Hd + lane];
    float v2 = h[(size_t)(n0 + 2) * Hd + lane];
    float v3 = h[(size_t)(n0 + 3) * Hd + lane];
    if (b0 == b1 && b0 == b2 && b0 == b3) {
        unsafeAtomicAdd(&g[(size_t)b0 * Hd + lane], v0 + v1 + v2 + v3);
    } else {
        unsafeAtomicAdd(&g[(size_t)b0 * Hd + lane], v0);
        unsafeAtomicAdd(&g[(size_t)b1 * Hd + lane], v1);
        unsafeAtomicAdd(&g[(size_t)b2 * Hd + lane], v2);
        unsafeAtomicAdd(&g[(size_t)b3 * Hd + lane], v3);
    }
}

// ---- head: relu(g@lin1+b1)@lin2+b2, one wave per graph ----
__global__ void k_head(const float* __restrict__ g, const float* __restrict__ w1,
                       const float* __restrict__ b1, const float* __restrict__ w2,
                       const float* __restrict__ b2, float* __restrict__ out) {
    __shared__ float t[4][Hd];
    int wv = threadIdx.x >> 6;
    int lane = threadIdx.x & 63;
    int gi = blockIdx.x * 4 + wv;
    float acc = b1[lane];
    for (int k = 0; k < Hd; k++) acc += g[(size_t)gi * Hd + k] * w1[k * Hd + lane];
    t[wv][lane] = reluf(acc);
    __syncthreads();
    if (lane < Od) {
        float o = b2[lane];
        for (int k = 0; k < Hd; k++) o += t[wv][k] * w2[k * Od + lane];
        out[(size_t)gi * Od + lane] = o;
    }
}

extern "C" void kernel_launch(void* const* d_in, const int* in_sizes, int n_in,
                              void* d_out, int out_size, void* d_ws, size_t ws_size,
                              hipStream_t stream) {
    const float* x      = (const float*)d_in[0];
    const float* ea     = (const float*)d_in[1];
    const int*   eidx   = (const int*)d_in[2];
    const int*   batch  = (const int*)d_in[3];
    const float* emb    = (const float*)d_in[4];
    const float* lin1_w = (const float*)d_in[5];
    const float* lin1_b = (const float*)d_in[6];
    const float* lin2_w = (const float*)d_in[7];
    const float* lin2_b = (const float*)d_in[8];
    const float* rgcn_w[2]    = {(const float*)d_in[9],  (const float*)d_in[15]};
    const float* rgcn_root[2] = {(const float*)d_in[10], (const float*)d_in[16]};
    const float* rgcn_b[2]    = {(const float*)d_in[11], (const float*)d_in[17]};
    const float* mf_wl[2]     = {(const float*)d_in[12], (const float*)d_in[18]};
    const float* mf_bl[2]     = {(const float*)d_in[13], (const float*)d_in[19]};
    const float* mf_wr[2]     = {(const float*)d_in[14], (const float*)d_in[20]};

    char* p = (char*)d_ws;
    float* h0   = (float*)p; p += sizeof(float) * (size_t)Nn * Hd;
    float* h1   = (float*)p; p += sizeof(float) * (size_t)Nn * Hd;
    float* agg  = (float*)p; p += sizeof(float) * (size_t)NSEG * Hd;
    float* gbuf = (float*)p; p += sizeof(float) * (size_t)Ng * Hd;
    int* seg    = (int*)p;   p += sizeof(int) * (size_t)Ne;
    int* ssrc   = (int*)p;   p += sizeof(int) * (size_t)Ne;
    int* cnt    = (int*)p;   p += sizeof(int) * (size_t)NSEG;   // contiguous with bcnt/bfill
    int* bcnt   = (int*)p;   p += sizeof(int) * 16;
    int* bfill  = (int*)p;   p += sizeof(int) * 16;
    int* off    = (int*)p;   p += sizeof(int) * (size_t)(NSEG + 1);
    int* fill   = (int*)p;   p += sizeof(int) * (size_t)NSEG;
    int* bsum   = (int*)p;   p += sizeof(int) * 1024;
    int* bbase  = (int*)p;   p += sizeof(int) * 16;
    int* order  = (int*)p;   p += sizeof(int) * (size_t)NPAD;

    hipMemsetAsync(cnt, 0, sizeof(int) * ((size_t)NSEG + 32), stream);
    hipMemsetAsync(order, 0xFF, sizeof(int) * (size_t)NPAD, stream);
    hipMemsetAsync(gbuf, 0, sizeof(float) * (size_t)Ng * Hd, stream);

    k_rel_seg<<<Ne / 256, 256, 0, stream>>>((const float4*)ea, eidx, seg, cnt);
    k_scan1<<<SCAN_BLK, 256, 0, stream>>>(cnt, off, bsum);
    k_scan2<<<1, 1024, 0, stream>>>(bsum);
    k_scan3<<<SCAN_BLK, 256, 0, stream>>>(off, bsum, fill);
    k_scatter<<<Ne / 256, 256, 0, stream>>>(eidx, seg, fill, ssrc);
    k_embed<<<Nn / 4, 256, 0, stream>>>(x, emb, h0);
    k_bucket_count<<<(Nn + 255) / 256, 256, 0, stream>>>(off, bcnt);
    k_bucket_prefix<<<1, 64, 0, stream>>>(bcnt, bbase);
    k_bucket_scatter<<<(Nn + 255) / 256, 256, 0, stream>>>(off, bbase, bfill, order);

    float* hin = h0;
    float* hout = h1;
    for (int b = 0; b < 2; b++) {
        k_rgcn_agg<<<NSEG / 4, 256, 0, stream>>>(hin, off, ssrc, agg);
        k_rgcn_xform<<<Nn / 16, 256, 0, stream>>>(hin, agg, rgcn_w[b], rgcn_root[b],
                                                  rgcn_b[b], hout);
        k_mf_agg<<<Nn / 4, 256, 0, stream>>>(hout, off, ssrc, agg);
        k_mf_xform<<<(NPAD / 4 + 3) / 4, 256, 0, stream>>>(hout, agg, order, mf_wl[b], mf_bl[b],
                                                           mf_wr[b], hin);
        // block output is back in hin for the next block
    }
    k_pool<<<Nn / 16, 256, 0, stream>>>(hin, batch, gbuf);
    k_head<<<Ng / 4, 256, 0, stream>>>(gbuf, lin1_w, lin1_b, lin2_w, lin2_b, (float*)d_out);
}